// Round 6
// baseline (12693.621 us; speedup 1.0000x reference)
//
#include <hip/hip_runtime.h>

#define Bb 8
#define Ss 4096
#define Dd 512
#define Hh 1024
#define CSc 64
#define NCn 64
#define MROW 512  // Bb*CSc
#define GRIDB 256 // persistent scan grid (1 block/CU)

typedef unsigned short ushort_t;
typedef short s8v __attribute__((ext_vector_type(8)));          // 8 bf16 for MFMA A/B
typedef unsigned short u8v __attribute__((ext_vector_type(8))); // raw 8x bf16 storage
typedef float f4v __attribute__((ext_vector_type(4)));          // MFMA C/D
typedef float f4x __attribute__((ext_vector_type(4)));          // 16B float vector

enum { PH_PROJ=0, PH_H1, PH_PRED, PH_D1, PH_UPD1, PH_UPD2, PH_H1Q, PH_R, PH_OUTC };

struct Ptrs {
  const float *x, *Wk, *Wv, *Wq, *Wout, *W1, *W2;
  ushort_t *kbuf, *vbuf, *qbuf, *rbuf;
  ushort_t *h1, *a1, *d1b, *d2b;
  ushort_t *e1, *e2;            // bf16 effective weights f2b(W+Wd), written at UPD
  float *Wd1, *M1, *Wd2, *M2;   // block-private cached state (fixed tile->bid map)
  float *gates;
  float *out;
};

__device__ __forceinline__ float b2f(ushort_t u){
  union { unsigned int i; float f; } c; c.i = ((unsigned int)u) << 16; return c.f;
}
__device__ __forceinline__ ushort_t f2b(float f){
  union { float f; unsigned int i; } c; c.f = f;
  unsigned int i = c.i;
  i += 0x7fffu + ((i >> 16) & 1u);   // RTNE
  return (ushort_t)(i >> 16);
}
__device__ __forceinline__ float sig_(float v){ return 1.0f/(1.0f+__expf(-v)); }
__device__ __forceinline__ float silu_(float v){ return v*sig_(v); }
__device__ __forceinline__ float dsilu_(float v){ float s=sig_(v); return s*(1.0f + v*(1.0f-s)); }
__device__ __forceinline__ float clip1_(float v){ return fminf(fmaxf(v,-1.0f),1.0f); }
// row index m=(b,c) -> flat [b*S + nc*64 + c]*D + d
__device__ __forceinline__ size_t cidx(int m, int d, int nc){
  return ((size_t)((m>>6)*Ss) + nc*CSc + (m&63))*Dd + d;
}

// ---- coherent-point accessors: volatile => bypass L1/L2 (cross-block data) -----
__device__ __forceinline__ void vst1 (ushort_t* a, ushort_t v){ *(volatile ushort_t*)a = v; }
__device__ __forceinline__ ushort_t vldu(const ushort_t* a){ return *(const volatile ushort_t*)a; }

template<bool VOL>
__device__ __forceinline__ u8v ld8(const ushort_t* a){
  if constexpr (VOL) return *(const volatile u8v*)a;
  else               return *(const u8v*)a;
}

// ---- LDS layouts: 64 rows x 512 shorts per panel ----
// swz: XOR-swizzle for row-staged panels (b128 write whole row, b128 read cols)
__device__ __forceinline__ int swz(int r, int c){ return r*512 + (c ^ ((r&7)<<3)); }
// skw: skewed layout for transpose-staged panels: <=2-way on scalar scatter writes
// (bank = f(lane>>3) only) and on b128 MFMA reads. Skew multiple of 8 keeps 16B align.
__device__ __forceinline__ int skw(int m, int c){
  return m*512 + ((c + 8*((m + (m>>3)) & 63)) & 511);
}

// ======================= whole-panel staging (wave-contiguous) ==================
// Row-major source -> Dst[swz(r,c)]. Each wave reads ONE FULL 1KB row per iter:
// lane l covers bytes [l*16, l*16+16) -> every 64B fabric line fully consumed.
template<bool VOL>
__device__ __forceinline__ void stage_rows(const ushort_t* base, size_t stride,
                                           int kp, ushort_t* Dst){
  const int t = threadIdx.x;
  const int c = (t&63)*8;
  #pragma unroll
  for (int j=0;j<16;j++){
    int r = j*4 + (t>>6);
    u8v v = ld8<VOL>(base + (size_t)r*stride + kp + c);
    *(u8v*)&Dst[swz(r,c)] = v;
  }
}
// Row-major fp32 source (cached weights): convert to bf16. 32B/lane = full row/wave.
__device__ __forceinline__ void stage_rows_f32(const float* base, size_t stride,
                                               int kp, ushort_t* Dst){
  const int t = threadIdx.x;
  const int c = (t&63)*8;
  #pragma unroll
  for (int j=0;j<16;j++){
    int r = j*4 + (t>>6);
    const float* s = base + (size_t)r*stride + kp + c;
    f4x f0 = *(const f4x*)s, f1 = *(const f4x*)(s+4);
    u8v o;
    o[0]=f2b(f0[0]); o[1]=f2b(f0[1]); o[2]=f2b(f0[2]); o[3]=f2b(f0[3]);
    o[4]=f2b(f1[0]); o[5]=f2b(f1[1]); o[6]=f2b(f1[2]); o[7]=f2b(f1[3]);
    *(u8v*)&Dst[swz(r,c)] = o;
  }
}
// Transpose stage: source slab is 512 rows x 128B (cols [coloff, coloff+64)).
// Read ROW-CONTIGUOUS (8 lanes x 16B = the full 128B row -> 2 full lines), then
// scalar-scatter into skewed LDS: Dst[skw(m,k)] = src[k][coloff+m].
// CHUNK: row k maps through the chunked token layout (kbuf).
template<bool VOL, bool CHUNK>
__device__ __forceinline__ void stage_tr(const ushort_t* base, size_t stride,
                                         int coloff, ushort_t* Dst){
  const int t = threadIdx.x;
  const int mb = (t&7)*8;
  #pragma unroll
  for (int i=0;i<16;i++){
    int kk = i*32 + (t>>3);
    size_t row = CHUNK ? (size_t)((kk>>6)*Ss + (kk&63)) : (size_t)kk;
    u8v v = ld8<VOL>(base + row*stride + coloff + mb);
    #pragma unroll
    for (int j=0;j<8;j++) Dst[skw(mb+j, kk)] = v[j];
  }
}

// ============ MFMA bf16 GEMM: 64x64 tile, 4 waves 2x2, whole-panel K=512 ========
template<int PHASE, int KD>
__device__ __forceinline__ void gemm_body(const Ptrs& p, int nc, int bx, int by,
                                          const float* Wp, ushort_t* Cp,
                                          ushort_t* As, ushort_t* Bs){
  constexpr bool SKA = (PHASE==PH_UPD1 || PHASE==PH_UPD2);
  constexpr bool SKB = (PHASE==PH_UPD1 || PHASE==PH_UPD2 || PHASE==PH_D1);
  const int tid = threadIdx.x;
  const int m0 = bx*64, n0 = by*64;
  const int wave = tid>>6, lane = tid&63;
  const int wm = wave&1, wn = wave>>1;
  const int quad = lane>>4, l16 = lane&15;

  f4v zz = {0.f,0.f,0.f,0.f};
  f4v acc[2][2];
  acc[0][0]=zz; acc[0][1]=zz; acc[1][0]=zz; acc[1][1]=zz;

  for (int kp=0; kp<KD; kp+=512){
    if (kp) __syncthreads();   // all waves done reading LDS before re-stage
    // ---------------- stage A panel ----------------
    if constexpr (PHASE==PH_PROJ)      stage_rows_f32(&p.x[(size_t)m0*Dd], Dd, kp, As);
    else if constexpr (PHASE==PH_H1)   stage_rows<false>(&p.kbuf[((size_t)(m0>>6)*Ss + (size_t)nc*CSc)*Dd], Dd, kp, As);
    else if constexpr (PHASE==PH_H1Q)  stage_rows<false>(&p.qbuf[((size_t)(m0>>6)*Ss + (size_t)nc*CSc)*Dd], Dd, kp, As);
    else if constexpr (PHASE==PH_PRED) stage_rows<true >(&p.a1[(size_t)m0*Hh], Hh, kp, As);
    else if constexpr (PHASE==PH_R)    stage_rows<true >(&p.d1b[(size_t)m0*Hh], Hh, kp, As);
    else if constexpr (PHASE==PH_D1)   stage_rows<true >(&p.d2b[(size_t)m0*Dd], Dd, kp, As);
    else if constexpr (PHASE==PH_OUTC) stage_rows<true >(&p.rbuf[(size_t)m0*Dd], Dd, kp, As);
    else if constexpr (PHASE==PH_UPD1) stage_tr<true,false>(p.d1b, Hh, m0, As);
    else /* PH_UPD2 */                 stage_tr<true,false>(p.d2b, Dd, m0, As);
    // ---------------- stage B panel ----------------
    if constexpr (PHASE==PH_PROJ)      stage_rows_f32(&Wp[(size_t)n0*Dd], Dd, kp, Bs);
    else if constexpr (PHASE==PH_OUTC) stage_rows_f32(&p.Wout[(size_t)n0*Dd], Dd, kp, Bs);
    else if constexpr (PHASE==PH_H1 || PHASE==PH_H1Q)
                                       stage_rows<true>(&p.e1[(size_t)n0*Dd], Dd, kp, Bs);
    else if constexpr (PHASE==PH_PRED || PHASE==PH_R)
                                       stage_rows<true>(&p.e2[(size_t)n0*Hh], Hh, kp, Bs);
    else if constexpr (PHASE==PH_D1)   stage_tr<true,false>(p.e2, Hh, n0, Bs);
    else if constexpr (PHASE==PH_UPD2) stage_tr<true,false>(p.a1, Hh, n0, Bs);
    else /* PH_UPD1 */                 stage_tr<false,true>(p.kbuf + (size_t)nc*CSc*Dd, Dd, n0, Bs);
    __syncthreads();
    // ---------------- MFMA over the 512-K panel ----------------
    #pragma unroll
    for (int ks=0; ks<16; ++ks){
      const int ca = ks*32 + quad*8;
      const int ra0 = wm*32 + l16, ra1 = ra0 + 16;
      const int rb0 = wn*32 + l16, rb1 = rb0 + 16;
      s8v a0, a1f, b0, b1f;
      if constexpr (SKA){ a0 = *(const s8v*)&As[skw(ra0,ca)]; a1f = *(const s8v*)&As[skw(ra1,ca)]; }
      else              { a0 = *(const s8v*)&As[swz(ra0,ca)]; a1f = *(const s8v*)&As[swz(ra1,ca)]; }
      if constexpr (SKB){ b0 = *(const s8v*)&Bs[skw(rb0,ca)]; b1f = *(const s8v*)&Bs[skw(rb1,ca)]; }
      else              { b0 = *(const s8v*)&Bs[swz(rb0,ca)]; b1f = *(const s8v*)&Bs[swz(rb1,ca)]; }
      acc[0][0] = __builtin_amdgcn_mfma_f32_16x16x32_bf16(a0,  b0,  acc[0][0], 0,0,0);
      acc[0][1] = __builtin_amdgcn_mfma_f32_16x16x32_bf16(a0,  b1f, acc[0][1], 0,0,0);
      acc[1][0] = __builtin_amdgcn_mfma_f32_16x16x32_bf16(a1f, b0,  acc[1][0], 0,0,0);
      acc[1][1] = __builtin_amdgcn_mfma_f32_16x16x32_bf16(a1f, b1f, acc[1][1], 0,0,0);
    }
  }

  // ---------------- epilogue: D row = quad*4+r, col = l16 ----------------
  float al=0.f, lr=0.f, et=0.f;
  if constexpr (PHASE==PH_UPD1 || PHASE==PH_UPD2) {
    al = p.gates[nc]; lr = p.gates[NCn+nc]; et = p.gates[2*NCn+nc];
  }
  #pragma unroll
  for (int mf=0; mf<2; mf++) {
    #pragma unroll
    for (int nf=0; nf<2; nf++) {
      #pragma unroll
      for (int r=0; r<4; r++) {
        int m = m0 + wm*32 + mf*16 + quad*4 + r;
        int n = n0 + wn*32 + nf*16 + l16;
        float v = acc[mf][nf][r];
        if constexpr (PHASE==PH_PROJ)      Cp[(size_t)m*Dd+n] = f2b(v);
        else if constexpr (PHASE==PH_OUTC) p.out[cidx(m,n,nc)] = v;
        else if constexpr (PHASE==PH_H1) {
          vst1(&p.h1[(size_t)m*Hh+n], f2b(v));
          vst1(&p.a1[(size_t)m*Hh+n], f2b(silu_(v)));
        }
        else if constexpr (PHASE==PH_H1Q)  vst1(&p.d1b[(size_t)m*Hh+n], f2b(silu_(v)));
        else if constexpr (PHASE==PH_PRED) {
          float e = clip1_(v - b2f(p.vbuf[cidx(m,n,nc)]));
          vst1(&p.d2b[(size_t)m*Dd+n], f2b(0.03125f*e));   // scale = 2/CS
        }
        else if constexpr (PHASE==PH_R)    vst1(&p.rbuf[(size_t)m*Dd+n], f2b(v));
        else if constexpr (PHASE==PH_D1)
          vst1(&p.d1b[(size_t)m*Hh+n], f2b(v * dsilu_(b2f(vldu(&p.h1[(size_t)m*Hh+n])))));
        else if constexpr (PHASE==PH_UPD1) {
          float g = clip1_(v);
          size_t idx = (size_t)m*Dd+n;
          float m1 = et*p.M1[idx] - lr*g;        // cached: block-private state
          p.M1[idx] = m1;
          float wd = (1.0f-al)*p.Wd1[idx] + m1;
          p.Wd1[idx] = wd;
          vst1(&p.e1[idx], f2b(p.W1[idx] + wd)); // publish bf16 effective weight
        }
        else if constexpr (PHASE==PH_UPD2) {
          float g = clip1_(v);
          size_t idx = (size_t)m*Hh+n;
          float m2 = et*p.M2[idx] - lr*g;
          p.M2[idx] = m2;
          float wd = (1.0f-al)*p.Wd2[idx] + m2;
          p.Wd2[idx] = wd;
          vst1(&p.e2[idx], f2b(p.W2[idx] + wd));
        }
      }
    }
  }
}

// ---------------- projections (massively parallel, normal launch) ---------------
__global__ __launch_bounds__(256,1) void gk_proj(Ptrs p){
  __shared__ ushort_t As[64*512];
  __shared__ ushort_t Bs[64*512];
  const float* Wp = blockIdx.z==0 ? p.Wk : (blockIdx.z==1 ? p.Wv : p.Wq);
  ushort_t*    Cp = blockIdx.z==0 ? p.kbuf : (blockIdx.z==1 ? p.vbuf : p.qbuf);
  gemm_body<PH_PROJ,Dd>(p, 0, blockIdx.x, blockIdx.y, Wp, Cp, As, Bs);
}

// ---------------- atomic-free distributed grid barrier ---------------------------
__device__ __forceinline__ void gridbar(volatile unsigned* arr, volatile unsigned* rel,
                                        unsigned ep){
  __syncthreads();                      // drains this block's data stores (vmcnt 0)
  if (blockIdx.x == 0){
    int t = threadIdx.x;
    if (t > 0 && t < GRIDB){
      while (arr[t*16] < ep) __builtin_amdgcn_s_sleep(2);
    }
    __syncthreads();                    // all watchers done
    if (t == 0) rel[0] = ep;
  } else {
    if (threadIdx.x == 0){
      arr[blockIdx.x*16] = ep;
      while (rel[0] < ep) __builtin_amdgcn_s_sleep(2);
    }
  }
  __syncthreads();
  asm volatile("" ::: "memory");
}

// ---------------- persistent fused scan: 4 epochs/chunk, pipelined across chunks
// Epoch A: UPD1(nc)[128] + UPD2(nc)[128]   (also publishes e1,e2)
// Epoch B: H1Q(nc)[128] + H1(nc+1)[128]
// Epoch C: R(nc)[64]    + PRED(nc+1)[64]
// Epoch D: OUTC(nc)[64] + D1(nc+1)[128]
__global__ __launch_bounds__(256,1) void scan_k(Ptrs p, unsigned* arr, unsigned* rel){
  __shared__ ushort_t As[64*512];
  __shared__ ushort_t Bs[64*512];
  const int bid = blockIdx.x;
  unsigned ep = 0;

  // prologue: chunk 0 head of the dependency chain
  if (bid < 128) gemm_body<PH_H1,  Dd>(p, 0, bid>>4, bid&15, nullptr,nullptr, As,Bs);
  gridbar(arr, rel, ++ep);
  if (bid < 64)  gemm_body<PH_PRED,Hh>(p, 0, bid>>3, bid&7,  nullptr,nullptr, As,Bs);
  gridbar(arr, rel, ++ep);
  if (bid < 128) gemm_body<PH_D1,  Dd>(p, 0, bid>>4, bid&15, nullptr,nullptr, As,Bs);
  gridbar(arr, rel, ++ep);

  for (int nc = 0; nc < NCn; ++nc) {
    const bool more = (nc+1 < NCn);
    // ---- Epoch A: weight updates (disjoint outputs Wd1/M1/e1 vs Wd2/M2/e2) ----
    if (bid < 128) gemm_body<PH_UPD1,MROW>(p, nc, bid>>3, bid&7, nullptr,nullptr, As,Bs);
    else           gemm_body<PH_UPD2,MROW>(p, nc, (bid-128)>>4, (bid-128)&15, nullptr,nullptr, As,Bs);
    gridbar(arr, rel, ++ep);
    // ---- Epoch B: both consumers of e1_new ----
    if (bid < 128)      gemm_body<PH_H1Q,Dd>(p, nc,   bid>>4, bid&15, nullptr,nullptr, As,Bs);
    else if (more)      gemm_body<PH_H1, Dd>(p, nc+1, (bid-128)>>4, (bid-128)&15, nullptr,nullptr, As,Bs);
    gridbar(arr, rel, ++ep);
    // ---- Epoch C: both consumers of e2_new ----
    if (bid < 64)               gemm_body<PH_R,   Hh>(p, nc,   bid>>3, bid&7, nullptr,nullptr, As,Bs);
    else if (bid < 128 && more) gemm_body<PH_PRED,Hh>(p, nc+1, (bid-64)>>3, (bid-64)&7, nullptr,nullptr, As,Bs);
    gridbar(arr, rel, ++ep);
    // ---- Epoch D: output proj of nc + backward of nc+1 ----
    if (bid < 64)               gemm_body<PH_OUTC,Dd>(p, nc,   bid>>3, bid&7, nullptr,nullptr, As,Bs);
    else if (bid < 192 && more) gemm_body<PH_D1, Dd>(p, nc+1, (bid-64)>>4, (bid-64)&15, nullptr,nullptr, As,Bs);
    gridbar(arr, rel, ++ep);
  }
}

// ---------------- zero helper ----------------------------------------------------
__global__ __launch_bounds__(256)
void zero_k(float* __restrict__ ptr, int n){
  int i = blockIdx.x*256 + threadIdx.x;
  int stride = gridDim.x*256;
  for (; i < n; i += stride) ptr[i] = 0.0f;
}

// ---------------- init bf16 effective weights e1=f2b(W1), e2=f2b(W2) -------------
__global__ __launch_bounds__(256)
void einit_k(const float* __restrict__ W1, const float* __restrict__ W2,
             ushort_t* __restrict__ e1, ushort_t* __restrict__ e2){
  int i = blockIdx.x*256 + threadIdx.x;
  int stride = gridDim.x*256;
  for (; i < Hh*Dd; i += stride){
    e1[i] = f2b(W1[i]);
    e2[i] = f2b(W2[i]);
  }
}

// ---------------- halo save (last 3 rows of each chunk, pre-conv) ----------------
__global__ void halo_k(const ushort_t* __restrict__ kbuf, const ushort_t* __restrict__ vbuf,
                       const ushort_t* __restrict__ qbuf, ushort_t* __restrict__ halo){
  int bid = blockIdx.x;
  int t = bid / (NCn*Bb);
  int rem = bid % (NCn*Bb);
  int nc = rem / Bb, b = rem % Bb;
  const ushort_t* src = (t==0)?kbuf:((t==1)?vbuf:qbuf);
  ushort_t* dst = halo + (((size_t)t*NCn + nc)*Bb + b)*3*Dd;
  for (int e = threadIdx.x; e < 3*Dd; e += 256){
    int j = e / Dd, d = e % Dd;
    int s = nc*CSc + 61 + j;
    dst[e] = src[((size_t)b*Ss + s)*Dd + d];
  }
}

// ---------------- in-place causal depthwise conv (K=4) ---------------------------
__global__ void conv_k(ushort_t* __restrict__ kbuf, ushort_t* __restrict__ vbuf, ushort_t* __restrict__ qbuf,
                       const float* __restrict__ ckw, const float* __restrict__ ckb,
                       const float* __restrict__ cvw, const float* __restrict__ cvb,
                       const float* __restrict__ cqw, const float* __restrict__ cqb,
                       const ushort_t* __restrict__ halo){
  int bid = blockIdx.x;
  int t = bid / (NCn*Bb);
  int rem = bid % (NCn*Bb);
  int nc = rem / Bb, b = rem % Bb;
  ushort_t* buf = (t==0)?kbuf:((t==1)?vbuf:qbuf);
  const float* cw = (t==0)?ckw:((t==1)?cvw:cqw);
  const float* cb = (t==0)?ckb:((t==1)?cvb:cqb);
  const ushort_t* hl = halo + (((size_t)t*NCn + (nc>0?nc-1:0))*Bb + b)*3*Dd;
  for (int rep=0; rep<2; ++rep){
    int d = threadIdx.x + rep*256;
    float w0 = cw[d*4+0], w1 = cw[d*4+1], w2 = cw[d*4+2], w3 = cw[d*4+3];
    float bias = cb[d];
    float p1, p2, p3;
    if (nc == 0) { p1=p2=p3=0.0f; }
    else { p1 = b2f(hl[2*Dd+d]); p2 = b2f(hl[1*Dd+d]); p3 = b2f(hl[0*Dd+d]); }
    ushort_t* row = buf + ((size_t)b*Ss + nc*CSc)*Dd + d;
    for (int c=0;c<CSc;++c){
      float cur = b2f(row[(size_t)c*Dd]);
      float o = w3*cur + w2*p1 + w1*p2 + w0*p3 + bias;
      p3 = p2; p2 = p1; p1 = cur;
      row[(size_t)c*Dd] = f2b(o);
    }
  }
}

// ---------------- per-chunk scalar gates -----------------------------------------
__global__ __launch_bounds__(256)
void gates_k(const float* __restrict__ x,
             const float* __restrict__ wd, const float* __restrict__ bd,
             const float* __restrict__ wl, const float* __restrict__ bl,
             const float* __restrict__ we, const float* __restrict__ be,
             float* __restrict__ gates){
  int nc = blockIdx.x;
  int wave = threadIdx.x >> 6, lane = threadIdx.x & 63;
  __shared__ float red[4][3];
  float accA=0.f, accL=0.f, accE=0.f;
  float bdv = bd[0], blv = bl[0], bev = be[0];
  for (int pi = wave; pi < Bb*CSc; pi += 4) {
    int b = pi / CSc, c = pi % CSc;
    const float* xr = x + ((size_t)b*Ss + nc*CSc + c)*Dd + lane*8;
    float da=0.f, dl=0.f, de=0.f;
    #pragma unroll
    for (int u=0;u<8;++u){
      float xv = xr[u];
      int d = lane*8+u;
      da += xv*wd[d]; dl += xv*wl[d]; de += xv*we[d];
    }
    #pragma unroll
    for (int off=32; off; off>>=1){
      da += __shfl_down(da, off);
      dl += __shfl_down(dl, off);
      de += __shfl_down(de, off);
    }
    if (lane==0){
      accA += sig_(da + bdv);
      accL += sig_(dl + blv);
      accE += sig_(de + bev);
    }
  }
  if (lane==0){ red[wave][0]=accA; red[wave][1]=accL; red[wave][2]=accE; }
  __syncthreads();
  if (threadIdx.x==0){
    float a=0.f,l=0.f,e=0.f;
    for (int w=0;w<4;w++){ a+=red[w][0]; l+=red[w][1]; e+=red[w][2]; }
    gates[nc]        = a*(1.0f/512.0f);
    gates[NCn+nc]    = l*(1.0f/512.0f);
    gates[2*NCn+nc]  = e*(1.0f/512.0f);
  }
}

extern "C" void kernel_launch(void* const* d_in, const int* in_sizes, int n_in,
                              void* d_out, int out_size, void* d_ws, size_t ws_size,
                              hipStream_t stream) {
  (void)in_sizes; (void)n_in; (void)out_size;
  const float* x       = (const float*)d_in[0];
  const float* Wk      = (const float*)d_in[1];
  const float* Wv      = (const float*)d_in[2];
  const float* Wq      = (const float*)d_in[3];
  const float* Wout    = (const float*)d_in[4];
  const float* ckw     = (const float*)d_in[5];
  const float* ckb     = (const float*)d_in[6];
  const float* cvw     = (const float*)d_in[7];
  const float* cvb     = (const float*)d_in[8];
  const float* cqw     = (const float*)d_in[9];
  const float* cqb     = (const float*)d_in[10];
  const float* w_decay = (const float*)d_in[11];
  const float* b_decay = (const float*)d_in[12];
  const float* w_lr    = (const float*)d_in[13];
  const float* b_lr    = (const float*)d_in[14];
  const float* w_eta   = (const float*)d_in[15];
  const float* b_eta   = (const float*)d_in[16];
  const float* W1      = (const float*)d_in[17];
  const float* W2      = (const float*)d_in[18];

  // ---- workspace carve: fp32 state first, then bf16 buffers ----
  char* base = (char*)d_ws;
  size_t off = 0;
  auto alloc_f = [&](size_t n)->float*   { float* r=(float*)(base+off);   off += n*4; return r; };
  auto alloc_b = [&](size_t n)->ushort_t*{ ushort_t* r=(ushort_t*)(base+off); off += n*2; off=(off+15)&~15ull; return r; };

  float* Wd1  = alloc_f((size_t)Hh*Dd);
  float* M1   = alloc_f((size_t)Hh*Dd);
  float* Wd2  = alloc_f((size_t)Dd*Hh);
  float* M2   = alloc_f((size_t)Dd*Hh);
  float* gates= alloc_f(3*NCn + 4);
  float* barf = alloc_f(GRIDB*16 + 16);   // arrive slots (64B-padded) + release word

  const size_t BSD = (size_t)Bb*Ss*Dd;
  ushort_t* kbuf = alloc_b(BSD);
  ushort_t* vbuf = alloc_b(BSD);
  ushort_t* qbuf = alloc_b(BSD);
  ushort_t* halo = alloc_b((size_t)3*NCn*Bb*3*Dd);
  ushort_t* h1   = alloc_b((size_t)MROW*Hh);
  ushort_t* a1   = alloc_b((size_t)MROW*Hh);
  ushort_t* d1b  = alloc_b((size_t)MROW*Hh);
  ushort_t* d2b  = alloc_b((size_t)MROW*Dd);
  ushort_t* rbuf = alloc_b((size_t)MROW*Dd);
  ushort_t* e1   = alloc_b((size_t)Hh*Dd);
  ushort_t* e2   = alloc_b((size_t)Dd*Hh);

  if (ws_size < off) return;  // clean fail instead of fault

  // zero scan state (Wd1,M1,Wd2,M2,gates,barrier contiguous fp32 block)
  zero_k<<<1024, 256, 0, stream>>>(Wd1, 4*Hh*Dd + (3*NCn+4) + (GRIDB*16+16));
  einit_k<<<512, 256, 0, stream>>>(W1, W2, e1, e2);

  Ptrs p;
  p.x=x; p.Wk=Wk; p.Wv=Wv; p.Wq=Wq; p.Wout=Wout; p.W1=W1; p.W2=W2;
  p.kbuf=kbuf; p.vbuf=vbuf; p.qbuf=qbuf; p.rbuf=rbuf;
  p.h1=h1; p.a1=a1; p.d1b=d1b; p.d2b=d2b;
  p.e1=e1; p.e2=e2;
  p.Wd1=Wd1; p.M1=M1; p.Wd2=Wd2; p.M2=M2;
  p.gates=gates; p.out=(float*)d_out;

  unsigned* arr = (unsigned*)barf;
  unsigned* rel = (unsigned*)(barf + GRIDB*16);

  // projections: k/v/q = bf16(x) @ bf16(W^T)
  gk_proj<<<dim3(Bb*Ss/64, Dd/64, 3), 256, 0, stream>>>(p);
  halo_k<<<3*NCn*Bb, 256, 0, stream>>>(kbuf, vbuf, qbuf, halo);
  conv_k<<<3*NCn*Bb, 256, 0, stream>>>(kbuf, vbuf, qbuf, ckw, ckb, cvw, cvb, cqw, cqb, halo);
  gates_k<<<NCn, 256, 0, stream>>>(x, w_decay, b_decay, w_lr, b_lr, w_eta, b_eta, gates);

  // fused persistent chunk scan: 1 launch, 259 grid barriers, coalesced UC staging
  scan_k<<<GRIDB, 256, 0, stream>>>(p, arr, rel);
}

// Round 7
// 12035.561 us; speedup vs baseline: 1.0547x; 1.0547x over previous
//
#include <hip/hip_runtime.h>

#define Bb 8
#define Ss 4096
#define Dd 512
#define Hh 1024
#define CSc 64
#define NCn 64
#define MROW 512  // Bb*CSc
#define GRIDB 256 // persistent scan grid (1 block/CU)

typedef unsigned short ushort_t;
typedef short s8v __attribute__((ext_vector_type(8)));          // 8 bf16 for MFMA A/B
typedef unsigned short u8v __attribute__((ext_vector_type(8))); // raw 8x bf16 storage
typedef float f4v __attribute__((ext_vector_type(4)));          // MFMA C/D
typedef float f4x __attribute__((ext_vector_type(4)));          // 16B float vector

enum { PH_PROJ=0, PH_H1, PH_PRED, PH_D1, PH_UPD1, PH_UPD2, PH_H1Q, PH_R, PH_OUTC };

struct Ptrs {
  const float *x, *Wk, *Wv, *Wq, *Wout, *W1, *W2;
  ushort_t *kbuf, *vbuf, *qbuf, *rbuf;
  ushort_t *h1, *a1, *d1b, *d2b;
  ushort_t *e1, *e2;            // bf16 effective weights f2b(W+Wd), written at UPD
  float *Wd1, *M1, *Wd2, *M2;   // block-private cached state (fixed tile->bid map)
  float *gates;
  float *out;
};

__device__ __forceinline__ float b2f(ushort_t u){
  union { unsigned int i; float f; } c; c.i = ((unsigned int)u) << 16; return c.f;
}
__device__ __forceinline__ ushort_t f2b(float f){
  union { float f; unsigned int i; } c; c.f = f;
  unsigned int i = c.i;
  i += 0x7fffu + ((i >> 16) & 1u);   // RTNE
  return (ushort_t)(i >> 16);
}
__device__ __forceinline__ float sig_(float v){ return 1.0f/(1.0f+__expf(-v)); }
__device__ __forceinline__ float silu_(float v){ return v*sig_(v); }
__device__ __forceinline__ float dsilu_(float v){ float s=sig_(v); return s*(1.0f + v*(1.0f-s)); }
__device__ __forceinline__ float clip1_(float v){ return fminf(fmaxf(v,-1.0f),1.0f); }
// row index m=(b,c) -> flat [b*S + nc*64 + c]*D + d
__device__ __forceinline__ size_t cidx(int m, int d, int nc){
  return ((size_t)((m>>6)*Ss) + nc*CSc + (m&63))*Dd + d;
}

// ---- UC (coherence-point) STORES for cross-block intermediates -----------------
// Producers write volatile (sc0 sc1, write-through past L2 -> memory-side L3).
// Consumers read CACHED; visibility comes from the per-epoch acquire fence (inv).
__device__ __forceinline__ void vst1 (ushort_t* a, ushort_t v){ *(volatile ushort_t*)a = v; }

template<bool VOL>
__device__ __forceinline__ u8v ld8(const ushort_t* a){
  if constexpr (VOL) return *(const volatile u8v*)a;
  else               return *(const u8v*)a;
}

// ---- LDS layouts: 64 rows x 512 shorts per panel ----
// swz: XOR-swizzle for row-staged panels (b128 write whole row, b128 read cols)
__device__ __forceinline__ int swz(int r, int c){ return r*512 + (c ^ ((r&7)<<3)); }
// skw: skewed layout for transpose-staged panels: <=2-way on scalar scatter writes
// and on b128 MFMA reads. Skew multiple of 8 keeps 16B align.
__device__ __forceinline__ int skw(int m, int c){
  return m*512 + ((c + 8*((m + (m>>3)) & 63)) & 511);
}

// ======================= whole-panel staging (wave-contiguous) ==================
// Row-major source -> Dst[swz(r,c)]. Each wave reads ONE FULL 1KB row per iter.
template<bool VOL>
__device__ __forceinline__ void stage_rows(const ushort_t* base, size_t stride,
                                           int kp, ushort_t* Dst){
  const int t = threadIdx.x;
  const int c = (t&63)*8;
  #pragma unroll
  for (int j=0;j<16;j++){
    int r = j*4 + (t>>6);
    u8v v = ld8<VOL>(base + (size_t)r*stride + kp + c);
    *(u8v*)&Dst[swz(r,c)] = v;
  }
}
// Row-major fp32 source (cached weights): convert to bf16.
__device__ __forceinline__ void stage_rows_f32(const float* base, size_t stride,
                                               int kp, ushort_t* Dst){
  const int t = threadIdx.x;
  const int c = (t&63)*8;
  #pragma unroll
  for (int j=0;j<16;j++){
    int r = j*4 + (t>>6);
    const float* s = base + (size_t)r*stride + kp + c;
    f4x f0 = *(const f4x*)s, f1 = *(const f4x*)(s+4);
    u8v o;
    o[0]=f2b(f0[0]); o[1]=f2b(f0[1]); o[2]=f2b(f0[2]); o[3]=f2b(f0[3]);
    o[4]=f2b(f1[0]); o[5]=f2b(f1[1]); o[6]=f2b(f1[2]); o[7]=f2b(f1[3]);
    *(u8v*)&Dst[swz(r,c)] = o;
  }
}
// Transpose stage: source slab is 512 rows x 128B (cols [coloff, coloff+64)).
// Read ROW-CONTIGUOUS (8 lanes x 16B = full 128B row), scatter into skewed LDS.
template<bool VOL, bool CHUNK>
__device__ __forceinline__ void stage_tr(const ushort_t* base, size_t stride,
                                         int coloff, ushort_t* Dst){
  const int t = threadIdx.x;
  const int mb = (t&7)*8;
  #pragma unroll
  for (int i=0;i<16;i++){
    int kk = i*32 + (t>>3);
    size_t row = CHUNK ? (size_t)((kk>>6)*Ss + (kk&63)) : (size_t)kk;
    u8v v = ld8<VOL>(base + row*stride + coloff + mb);
    #pragma unroll
    for (int j=0;j<8;j++) Dst[skw(mb+j, kk)] = v[j];
  }
}

// ============ MFMA bf16 GEMM: 64x64 tile, 4 waves 2x2, whole-panel K=512 ========
template<int PHASE, int KD>
__device__ __forceinline__ void gemm_body(const Ptrs& p, int nc, int bx, int by,
                                          const float* Wp, ushort_t* Cp,
                                          ushort_t* As, ushort_t* Bs){
  constexpr bool SKA = (PHASE==PH_UPD1 || PHASE==PH_UPD2);
  constexpr bool SKB = (PHASE==PH_UPD1 || PHASE==PH_UPD2 || PHASE==PH_D1);
  const int tid = threadIdx.x;
  const int m0 = bx*64, n0 = by*64;
  const int wave = tid>>6, lane = tid&63;
  const int wm = wave&1, wn = wave>>1;
  const int quad = lane>>4, l16 = lane&15;

  f4v zz = {0.f,0.f,0.f,0.f};
  f4v acc[2][2];
  acc[0][0]=zz; acc[0][1]=zz; acc[1][0]=zz; acc[1][1]=zz;

  for (int kp=0; kp<KD; kp+=512){
    if (kp) __syncthreads();   // all waves done reading LDS before re-stage
    // ---------------- stage A panel (ALL CACHED reads now) ----------------
    if constexpr (PHASE==PH_PROJ)      stage_rows_f32(&p.x[(size_t)m0*Dd], Dd, kp, As);
    else if constexpr (PHASE==PH_H1)   stage_rows<false>(&p.kbuf[((size_t)(m0>>6)*Ss + (size_t)nc*CSc)*Dd], Dd, kp, As);
    else if constexpr (PHASE==PH_H1Q)  stage_rows<false>(&p.qbuf[((size_t)(m0>>6)*Ss + (size_t)nc*CSc)*Dd], Dd, kp, As);
    else if constexpr (PHASE==PH_PRED) stage_rows<false>(&p.a1[(size_t)m0*Hh], Hh, kp, As);
    else if constexpr (PHASE==PH_R)    stage_rows<false>(&p.d1b[(size_t)m0*Hh], Hh, kp, As);
    else if constexpr (PHASE==PH_D1)   stage_rows<false>(&p.d2b[(size_t)m0*Dd], Dd, kp, As);
    else if constexpr (PHASE==PH_OUTC) stage_rows<false>(&p.rbuf[(size_t)m0*Dd], Dd, kp, As);
    else if constexpr (PHASE==PH_UPD1) stage_tr<false,false>(p.d1b, Hh, m0, As);
    else /* PH_UPD2 */                 stage_tr<false,false>(p.d2b, Dd, m0, As);
    // ---------------- stage B panel ----------------
    if constexpr (PHASE==PH_PROJ)      stage_rows_f32(&Wp[(size_t)n0*Dd], Dd, kp, Bs);
    else if constexpr (PHASE==PH_OUTC) stage_rows_f32(&p.Wout[(size_t)n0*Dd], Dd, kp, Bs);
    else if constexpr (PHASE==PH_H1 || PHASE==PH_H1Q)
                                       stage_rows<false>(&p.e1[(size_t)n0*Dd], Dd, kp, Bs);
    else if constexpr (PHASE==PH_PRED || PHASE==PH_R)
                                       stage_rows<false>(&p.e2[(size_t)n0*Hh], Hh, kp, Bs);
    else if constexpr (PHASE==PH_D1)   stage_tr<false,false>(p.e2, Hh, n0, Bs);
    else if constexpr (PHASE==PH_UPD2) stage_tr<false,false>(p.a1, Hh, n0, Bs);
    else /* PH_UPD1 */                 stage_tr<false,true>(p.kbuf + (size_t)nc*CSc*Dd, Dd, n0, Bs);
    __syncthreads();
    // ---------------- MFMA over the 512-K panel ----------------
    #pragma unroll
    for (int ks=0; ks<16; ++ks){
      const int ca = ks*32 + quad*8;
      const int ra0 = wm*32 + l16, ra1 = ra0 + 16;
      const int rb0 = wn*32 + l16, rb1 = rb0 + 16;
      s8v a0, a1f, b0, b1f;
      if constexpr (SKA){ a0 = *(const s8v*)&As[skw(ra0,ca)]; a1f = *(const s8v*)&As[skw(ra1,ca)]; }
      else              { a0 = *(const s8v*)&As[swz(ra0,ca)]; a1f = *(const s8v*)&As[swz(ra1,ca)]; }
      if constexpr (SKB){ b0 = *(const s8v*)&Bs[skw(rb0,ca)]; b1f = *(const s8v*)&Bs[skw(rb1,ca)]; }
      else              { b0 = *(const s8v*)&Bs[swz(rb0,ca)]; b1f = *(const s8v*)&Bs[swz(rb1,ca)]; }
      acc[0][0] = __builtin_amdgcn_mfma_f32_16x16x32_bf16(a0,  b0,  acc[0][0], 0,0,0);
      acc[0][1] = __builtin_amdgcn_mfma_f32_16x16x32_bf16(a0,  b1f, acc[0][1], 0,0,0);
      acc[1][0] = __builtin_amdgcn_mfma_f32_16x16x32_bf16(a1f, b0,  acc[1][0], 0,0,0);
      acc[1][1] = __builtin_amdgcn_mfma_f32_16x16x32_bf16(a1f, b1f, acc[1][1], 0,0,0);
    }
  }

  // ---------------- epilogue: D row = quad*4+r, col = l16 ----------------
  float al=0.f, lr=0.f, et=0.f;
  if constexpr (PHASE==PH_UPD1 || PHASE==PH_UPD2) {
    al = p.gates[nc]; lr = p.gates[NCn+nc]; et = p.gates[2*NCn+nc];
  }
  #pragma unroll
  for (int mf=0; mf<2; mf++) {
    #pragma unroll
    for (int nf=0; nf<2; nf++) {
      #pragma unroll
      for (int r=0; r<4; r++) {
        int m = m0 + wm*32 + mf*16 + quad*4 + r;
        int n = n0 + wn*32 + nf*16 + l16;
        float v = acc[mf][nf][r];
        if constexpr (PHASE==PH_PROJ)      Cp[(size_t)m*Dd+n] = f2b(v);
        else if constexpr (PHASE==PH_OUTC) p.out[cidx(m,n,nc)] = v;
        else if constexpr (PHASE==PH_H1) {
          vst1(&p.h1[(size_t)m*Hh+n], f2b(v));
          vst1(&p.a1[(size_t)m*Hh+n], f2b(silu_(v)));
        }
        else if constexpr (PHASE==PH_H1Q)  vst1(&p.d1b[(size_t)m*Hh+n], f2b(silu_(v)));
        else if constexpr (PHASE==PH_PRED) {
          float e = clip1_(v - b2f(p.vbuf[cidx(m,n,nc)]));
          vst1(&p.d2b[(size_t)m*Dd+n], f2b(0.03125f*e));   // scale = 2/CS
        }
        else if constexpr (PHASE==PH_R)    vst1(&p.rbuf[(size_t)m*Dd+n], f2b(v));
        else if constexpr (PHASE==PH_D1)
          vst1(&p.d1b[(size_t)m*Hh+n], f2b(v * dsilu_(b2f(p.h1[(size_t)m*Hh+n]))));
        else if constexpr (PHASE==PH_UPD1) {
          float g = clip1_(v);
          size_t idx = (size_t)m*Dd+n;
          float m1 = et*p.M1[idx] - lr*g;        // cached: block-private state
          p.M1[idx] = m1;
          float wd = (1.0f-al)*p.Wd1[idx] + m1;
          p.Wd1[idx] = wd;
          vst1(&p.e1[idx], f2b(p.W1[idx] + wd)); // publish bf16 effective weight
        }
        else if constexpr (PHASE==PH_UPD2) {
          float g = clip1_(v);
          size_t idx = (size_t)m*Hh+n;
          float m2 = et*p.M2[idx] - lr*g;
          p.M2[idx] = m2;
          float wd = (1.0f-al)*p.Wd2[idx] + m2;
          p.Wd2[idx] = wd;
          vst1(&p.e2[idx], f2b(p.W2[idx] + wd));
        }
      }
    }
  }
}

// ---------------- projections (massively parallel, normal launch) ---------------
__global__ __launch_bounds__(256,1) void gk_proj(Ptrs p){
  __shared__ ushort_t As[64*512];
  __shared__ ushort_t Bs[64*512];
  const float* Wp = blockIdx.z==0 ? p.Wk : (blockIdx.z==1 ? p.Wv : p.Wq);
  ushort_t*    Cp = blockIdx.z==0 ? p.kbuf : (blockIdx.z==1 ? p.vbuf : p.qbuf);
  gemm_body<PH_PROJ,Dd>(p, 0, blockIdx.x, blockIdx.y, Wp, Cp, As, Bs);
}

// ---------------- distributed grid barrier + per-CU acquire fence ----------------
// Arrive/release words are UC volatile (uncontended, padded slots). After release
// is observed, thread 0 issues ONE agent-scope acquire fence (buffer_inv: drops
// clean/stale lines, preserves dirty block-private state) so the block's CACHED
// reads of intermediates refetch through the coherent memory-side L3.
__device__ __forceinline__ void gridbar(volatile unsigned* arr, volatile unsigned* rel,
                                        unsigned ep){
  __syncthreads();                      // drains this block's UC data stores
  if (blockIdx.x == 0){
    int t = threadIdx.x;
    if (t > 0 && t < GRIDB){
      while (arr[t*16] < ep) __builtin_amdgcn_s_sleep(2);
    }
    __syncthreads();                    // all watchers done
    if (t == 0){
      rel[0] = ep;
      __builtin_amdgcn_fence(__ATOMIC_ACQUIRE, "agent");  // inv L1+L2 (1x per CU)
    }
  } else {
    if (threadIdx.x == 0){
      arr[blockIdx.x*16] = ep;
      while (rel[0] < ep) __builtin_amdgcn_s_sleep(2);
      __builtin_amdgcn_fence(__ATOMIC_ACQUIRE, "agent");  // inv L1+L2 (1x per CU)
    }
  }
  __syncthreads();
  asm volatile("" ::: "memory");
}

// ---------------- persistent fused scan: 4 epochs/chunk, pipelined across chunks
// Epoch A: UPD1(nc)[128] + UPD2(nc)[128]   (also publishes e1,e2)
// Epoch B: H1Q(nc)[128] + H1(nc+1)[128]
// Epoch C: R(nc)[64]    + PRED(nc+1)[64]
// Epoch D: OUTC(nc)[64] + D1(nc+1)[128]
__global__ __launch_bounds__(256,1) void scan_k(Ptrs p, unsigned* arr, unsigned* rel){
  __shared__ ushort_t As[64*512];
  __shared__ ushort_t Bs[64*512];
  const int bid = blockIdx.x;
  unsigned ep = 0;

  // prologue: chunk 0 head of the dependency chain
  if (bid < 128) gemm_body<PH_H1,  Dd>(p, 0, bid>>4, bid&15, nullptr,nullptr, As,Bs);
  gridbar(arr, rel, ++ep);
  if (bid < 64)  gemm_body<PH_PRED,Hh>(p, 0, bid>>3, bid&7,  nullptr,nullptr, As,Bs);
  gridbar(arr, rel, ++ep);
  if (bid < 128) gemm_body<PH_D1,  Dd>(p, 0, bid>>4, bid&15, nullptr,nullptr, As,Bs);
  gridbar(arr, rel, ++ep);

  for (int nc = 0; nc < NCn; ++nc) {
    const bool more = (nc+1 < NCn);
    // ---- Epoch A: weight updates (disjoint outputs Wd1/M1/e1 vs Wd2/M2/e2) ----
    if (bid < 128) gemm_body<PH_UPD1,MROW>(p, nc, bid>>3, bid&7, nullptr,nullptr, As,Bs);
    else           gemm_body<PH_UPD2,MROW>(p, nc, (bid-128)>>4, (bid-128)&15, nullptr,nullptr, As,Bs);
    gridbar(arr, rel, ++ep);
    // ---- Epoch B: both consumers of e1_new ----
    if (bid < 128)      gemm_body<PH_H1Q,Dd>(p, nc,   bid>>4, bid&15, nullptr,nullptr, As,Bs);
    else if (more)      gemm_body<PH_H1, Dd>(p, nc+1, (bid-128)>>4, (bid-128)&15, nullptr,nullptr, As,Bs);
    gridbar(arr, rel, ++ep);
    // ---- Epoch C: both consumers of e2_new ----
    if (bid < 64)               gemm_body<PH_R,   Hh>(p, nc,   bid>>3, bid&7, nullptr,nullptr, As,Bs);
    else if (bid < 128 && more) gemm_body<PH_PRED,Hh>(p, nc+1, (bid-64)>>3, (bid-64)&7, nullptr,nullptr, As,Bs);
    gridbar(arr, rel, ++ep);
    // ---- Epoch D: output proj of nc + backward of nc+1 ----
    if (bid < 64)               gemm_body<PH_OUTC,Dd>(p, nc,   bid>>3, bid&7, nullptr,nullptr, As,Bs);
    else if (bid < 192 && more) gemm_body<PH_D1, Dd>(p, nc+1, (bid-64)>>4, (bid-64)&15, nullptr,nullptr, As,Bs);
    gridbar(arr, rel, ++ep);
  }
}

// ---------------- zero helper ----------------------------------------------------
__global__ __launch_bounds__(256)
void zero_k(float* __restrict__ ptr, int n){
  int i = blockIdx.x*256 + threadIdx.x;
  int stride = gridDim.x*256;
  for (; i < n; i += stride) ptr[i] = 0.0f;
}

// ---------------- init bf16 effective weights e1=f2b(W1), e2=f2b(W2) -------------
// UC stores: e1/e2 must NEVER have dirty cached lines (scan overwrites them UC).
__global__ __launch_bounds__(256)
void einit_k(const float* __restrict__ W1, const float* __restrict__ W2,
             ushort_t* __restrict__ e1, ushort_t* __restrict__ e2){
  int i = blockIdx.x*256 + threadIdx.x;
  int stride = gridDim.x*256;
  for (; i < Hh*Dd; i += stride){
    vst1(&e1[i], f2b(W1[i]));
    vst1(&e2[i], f2b(W2[i]));
  }
}

// ---------------- halo save (last 3 rows of each chunk, pre-conv) ----------------
__global__ void halo_k(const ushort_t* __restrict__ kbuf, const ushort_t* __restrict__ vbuf,
                       const ushort_t* __restrict__ qbuf, ushort_t* __restrict__ halo){
  int bid = blockIdx.x;
  int t = bid / (NCn*Bb);
  int rem = bid % (NCn*Bb);
  int nc = rem / Bb, b = rem % Bb;
  const ushort_t* src = (t==0)?kbuf:((t==1)?vbuf:qbuf);
  ushort_t* dst = halo + (((size_t)t*NCn + nc)*Bb + b)*3*Dd;
  for (int e = threadIdx.x; e < 3*Dd; e += 256){
    int j = e / Dd, d = e % Dd;
    int s = nc*CSc + 61 + j;
    dst[e] = src[((size_t)b*Ss + s)*Dd + d];
  }
}

// ---------------- in-place causal depthwise conv (K=4) ---------------------------
__global__ void conv_k(ushort_t* __restrict__ kbuf, ushort_t* __restrict__ vbuf, ushort_t* __restrict__ qbuf,
                       const float* __restrict__ ckw, const float* __restrict__ ckb,
                       const float* __restrict__ cvw, const float* __restrict__ cvb,
                       const float* __restrict__ cqw, const float* __restrict__ cqb,
                       const ushort_t* __restrict__ halo){
  int bid = blockIdx.x;
  int t = bid / (NCn*Bb);
  int rem = bid % (NCn*Bb);
  int nc = rem / Bb, b = rem % Bb;
  ushort_t* buf = (t==0)?kbuf:((t==1)?vbuf:qbuf);
  const float* cw = (t==0)?ckw:((t==1)?cvw:cqw);
  const float* cb = (t==0)?ckb:((t==1)?cvb:cqb);
  const ushort_t* hl = halo + (((size_t)t*NCn + (nc>0?nc-1:0))*Bb + b)*3*Dd;
  for (int rep=0; rep<2; ++rep){
    int d = threadIdx.x + rep*256;
    float w0 = cw[d*4+0], w1 = cw[d*4+1], w2 = cw[d*4+2], w3 = cw[d*4+3];
    float bias = cb[d];
    float p1, p2, p3;
    if (nc == 0) { p1=p2=p3=0.0f; }
    else { p1 = b2f(hl[2*Dd+d]); p2 = b2f(hl[1*Dd+d]); p3 = b2f(hl[0*Dd+d]); }
    ushort_t* row = buf + ((size_t)b*Ss + nc*CSc)*Dd + d;
    for (int c=0;c<CSc;++c){
      float cur = b2f(row[(size_t)c*Dd]);
      float o = w3*cur + w2*p1 + w1*p2 + w0*p3 + bias;
      p3 = p2; p2 = p1; p1 = cur;
      row[(size_t)c*Dd] = f2b(o);
    }
  }
}

// ---------------- per-chunk scalar gates -----------------------------------------
__global__ __launch_bounds__(256)
void gates_k(const float* __restrict__ x,
             const float* __restrict__ wd, const float* __restrict__ bd,
             const float* __restrict__ wl, const float* __restrict__ bl,
             const float* __restrict__ we, const float* __restrict__ be,
             float* __restrict__ gates){
  int nc = blockIdx.x;
  int wave = threadIdx.x >> 6, lane = threadIdx.x & 63;
  __shared__ float red[4][3];
  float accA=0.f, accL=0.f, accE=0.f;
  float bdv = bd[0], blv = bl[0], bev = be[0];
  for (int pi = wave; pi < Bb*CSc; pi += 4) {
    int b = pi / CSc, c = pi % CSc;
    const float* xr = x + ((size_t)b*Ss + nc*CSc + c)*Dd + lane*8;
    float da=0.f, dl=0.f, de=0.f;
    #pragma unroll
    for (int u=0;u<8;++u){
      float xv = xr[u];
      int d = lane*8+u;
      da += xv*wd[d]; dl += xv*wl[d]; de += xv*we[d];
    }
    #pragma unroll
    for (int off=32; off; off>>=1){
      da += __shfl_down(da, off);
      dl += __shfl_down(dl, off);
      de += __shfl_down(de, off);
    }
    if (lane==0){
      accA += sig_(da + bdv);
      accL += sig_(dl + blv);
      accE += sig_(de + bev);
    }
  }
  if (lane==0){ red[wave][0]=accA; red[wave][1]=accL; red[wave][2]=accE; }
  __syncthreads();
  if (threadIdx.x==0){
    float a=0.f,l=0.f,e=0.f;
    for (int w=0;w<4;w++){ a+=red[w][0]; l+=red[w][1]; e+=red[w][2]; }
    gates[nc]        = a*(1.0f/512.0f);
    gates[NCn+nc]    = l*(1.0f/512.0f);
    gates[2*NCn+nc]  = e*(1.0f/512.0f);
  }
}

extern "C" void kernel_launch(void* const* d_in, const int* in_sizes, int n_in,
                              void* d_out, int out_size, void* d_ws, size_t ws_size,
                              hipStream_t stream) {
  (void)in_sizes; (void)n_in; (void)out_size;
  const float* x       = (const float*)d_in[0];
  const float* Wk      = (const float*)d_in[1];
  const float* Wv      = (const float*)d_in[2];
  const float* Wq      = (const float*)d_in[3];
  const float* Wout    = (const float*)d_in[4];
  const float* ckw     = (const float*)d_in[5];
  const float* ckb     = (const float*)d_in[6];
  const float* cvw     = (const float*)d_in[7];
  const float* cvb     = (const float*)d_in[8];
  const float* cqw     = (const float*)d_in[9];
  const float* cqb     = (const float*)d_in[10];
  const float* w_decay = (const float*)d_in[11];
  const float* b_decay = (const float*)d_in[12];
  const float* w_lr    = (const float*)d_in[13];
  const float* b_lr    = (const float*)d_in[14];
  const float* w_eta   = (const float*)d_in[15];
  const float* b_eta   = (const float*)d_in[16];
  const float* W1      = (const float*)d_in[17];
  const float* W2      = (const float*)d_in[18];

  // ---- workspace carve: fp32 state first, then bf16 buffers ----
  char* base = (char*)d_ws;
  size_t off = 0;
  auto alloc_f = [&](size_t n)->float*   { float* r=(float*)(base+off);   off += n*4; return r; };
  auto alloc_b = [&](size_t n)->ushort_t*{ ushort_t* r=(ushort_t*)(base+off); off += n*2; off=(off+15)&~15ull; return r; };

  float* Wd1  = alloc_f((size_t)Hh*Dd);
  float* M1   = alloc_f((size_t)Hh*Dd);
  float* Wd2  = alloc_f((size_t)Dd*Hh);
  float* M2   = alloc_f((size_t)Dd*Hh);
  float* gates= alloc_f(3*NCn + 4);
  float* barf = alloc_f(GRIDB*16 + 16);   // arrive slots (64B-padded) + release word

  const size_t BSD = (size_t)Bb*Ss*Dd;
  ushort_t* kbuf = alloc_b(BSD);
  ushort_t* vbuf = alloc_b(BSD);
  ushort_t* qbuf = alloc_b(BSD);
  ushort_t* halo = alloc_b((size_t)3*NCn*Bb*3*Dd);
  ushort_t* h1   = alloc_b((size_t)MROW*Hh);
  ushort_t* a1   = alloc_b((size_t)MROW*Hh);
  ushort_t* d1b  = alloc_b((size_t)MROW*Hh);
  ushort_t* d2b  = alloc_b((size_t)MROW*Dd);
  ushort_t* rbuf = alloc_b((size_t)MROW*Dd);
  ushort_t* e1   = alloc_b((size_t)Hh*Dd);
  ushort_t* e2   = alloc_b((size_t)Dd*Hh);

  if (ws_size < off) return;  // clean fail instead of fault

  // zero scan state (Wd1,M1,Wd2,M2,gates,barrier contiguous fp32 block)
  zero_k<<<1024, 256, 0, stream>>>(Wd1, 4*Hh*Dd + (3*NCn+4) + (GRIDB*16+16));
  einit_k<<<512, 256, 0, stream>>>(W1, W2, e1, e2);

  Ptrs p;
  p.x=x; p.Wk=Wk; p.Wv=Wv; p.Wq=Wq; p.Wout=Wout; p.W1=W1; p.W2=W2;
  p.kbuf=kbuf; p.vbuf=vbuf; p.qbuf=qbuf; p.rbuf=rbuf;
  p.h1=h1; p.a1=a1; p.d1b=d1b; p.d2b=d2b;
  p.e1=e1; p.e2=e2;
  p.Wd1=Wd1; p.M1=M1; p.Wd2=Wd2; p.M2=M2;
  p.gates=gates; p.out=(float*)d_out;

  unsigned* arr = (unsigned*)barf;
  unsigned* rel = (unsigned*)(barf + GRIDB*16);

  // projections: k/v/q = bf16(x) @ bf16(W^T)
  gk_proj<<<dim3(Bb*Ss/64, Dd/64, 3), 256, 0, stream>>>(p);
  halo_k<<<3*NCn*Bb, 256, 0, stream>>>(kbuf, vbuf, qbuf, halo);
  conv_k<<<3*NCn*Bb, 256, 0, stream>>>(kbuf, vbuf, qbuf, ckw, ckb, cvw, cvb, cqw, cqb, halo);
  gates_k<<<NCn, 256, 0, stream>>>(x, w_decay, b_decay, w_lr, b_lr, w_eta, b_eta, gates);

  // fused persistent chunk scan: cached panel reads + 1 acquire-inv per CU/epoch
  scan_k<<<GRIDB, 256, 0, stream>>>(p, arr, rel);
}